// Round 6
// baseline (816.105 us; speedup 1.0000x reference)
//
#include <hip/hip_runtime.h>
#include <hip/hip_bf16.h>
#include <cstdint>

// ---- problem constants ----
#define B_   2
#define L_   1024
#define H_   768
#define DI_  1536
#define DI2_ 3072      // 2*DI
#define DUP_ 12288     // 2*DI*4
#define DOUT_ 6144     // 4*DI
#define N_   16
#define R_   48
#define SPW  128       // padded ssm_p row stride (R + 2N = 80 -> 128)
#define BL_  2048      // B*L
#define C_   64        // scan chunks
#define CL_  16        // L_/C_ steps per chunk

typedef __bf16 bf16x8 __attribute__((ext_vector_type(8)));
typedef float  f32x4  __attribute__((ext_vector_type(4)));
typedef unsigned int u32;

__device__ __forceinline__ float silu_f(float v) {
    return v / (1.f + __expf(-v));
}

__device__ __forceinline__ void async_ld16(const void* g, void* lds) {
    __builtin_amdgcn_global_load_lds(
        (const __attribute__((address_space(1))) u32*)g,
        (__attribute__((address_space(3))) u32*)lds, 16, 0, 0);
}

__device__ __forceinline__ void cvt8(const float* __restrict__ s, __bf16* __restrict__ d, int i)
{
    const float4 a = *(const float4*)(s + i);
    const float4 b = *(const float4*)(s + i + 4);
    bf16x8 v;
    v[0] = (__bf16)a.x; v[1] = (__bf16)a.y; v[2] = (__bf16)a.z; v[3] = (__bf16)a.w;
    v[4] = (__bf16)b.x; v[5] = (__bf16)b.y; v[6] = (__bf16)b.z; v[7] = (__bf16)b.w;
    *(bf16x8*)(d + i) = v;
}

// ===========================================================================
// BK=64 MFMA GEMM body as a macro-expanded pattern, used monolithically in
// gemm_bf16 (keeps VGPR lean) and duplicated in g1_fused.
// LDS 32 KB: As[128][64], Bs[128][64] bf16, XOR chunk swizzle over 8 slots:
//   slot c of row r holds global k-chunk c^((r>>1)&7)
//   read slot for (kh,quad,row tr): (kh*4+quad)^((tr>>1)&7)
// -> uniform 8 lanes/bank-group on ds_read_b128 (conflict-free),
//    wave-uniform staging dest (base + lane*16B), 128B-line global coverage.
// 2 barriers + 1 vmcnt-drain per 64-K (half of BK=32).
// ===========================================================================
#define GEMM_BODY(EPI, ATOMIC, OutT, A, W, O, Kslice, lda, ldw, ldo, bm, bn, kbase)   \
{                                                                                      \
    __shared__ __bf16 As[128 * 64];                                                    \
    __shared__ __bf16 Bs[128 * 64];                                                    \
    const int tid  = threadIdx.x;                                                      \
    const int wave = tid >> 6, lane = tid & 63;                                        \
    const int wm = (wave >> 1) * 64, wn = (wave & 1) * 64;                              \
    const int quad = lane >> 4, tr = lane & 15;                                        \
    /* staging: thread covers rows srow + r4*32, slot tid&7 */                         \
    const int srow = tid >> 3;                                                         \
    const int gc   = (((tid & 7) ^ ((tid >> 4) & 7))) * 8;                             \
    const __bf16* Ag = A + (size_t)(bm + srow) * lda + kbase + gc;                     \
    const __bf16* Wg = W + (size_t)(bn + srow) * ldw + kbase + gc;                     \
    __bf16* Al = &As[tid * 8];                                                         \
    __bf16* Bl = &Bs[tid * 8];                                                         \
    /* fragment read bases: kh=0 slot q^h, kh=1 slot (q^h)^4 */                        \
    const int h8   = (tr >> 1) & 7;                                                    \
    const int sl0  = (quad ^ h8) * 8;                                                  \
    const __bf16* arp0 = &As[(wm + tr) * 64 + sl0];                                    \
    const __bf16* arp1 = &As[(wm + tr) * 64 + (sl0 ^ 32)];                             \
    const __bf16* brp0 = &Bs[(wn + tr) * 64 + sl0];                                    \
    const __bf16* brp1 = &Bs[(wn + tr) * 64 + (sl0 ^ 32)];                             \
    f32x4 acc[4][4];                                                                   \
    _Pragma("unroll")                                                                  \
    for (int i = 0; i < 4; ++i)                                                        \
        _Pragma("unroll")                                                              \
        for (int j = 0; j < 4; ++j) acc[i][j] = (f32x4){0.f, 0.f, 0.f, 0.f};           \
    for (int k0 = 0; k0 < Kslice; k0 += 64) {                                          \
        __syncthreads();                                                               \
        _Pragma("unroll")                                                              \
        for (int r4 = 0; r4 < 4; ++r4)                                                 \
            async_ld16(Ag + k0 + (size_t)r4 * 32 * lda, Al + r4 * 2048);               \
        _Pragma("unroll")                                                              \
        for (int r4 = 0; r4 < 4; ++r4)                                                 \
            async_ld16(Wg + k0 + (size_t)r4 * 32 * ldw, Bl + r4 * 2048);               \
        __syncthreads();                                                               \
        bf16x8 af[4], bfv[4];                                                          \
        _Pragma("unroll")                                                              \
        for (int i = 0; i < 4; ++i) af[i]  = *(const bf16x8*)(arp0 + i * 1024);        \
        _Pragma("unroll")                                                              \
        for (int j = 0; j < 4; ++j) bfv[j] = *(const bf16x8*)(brp0 + j * 1024);        \
        _Pragma("unroll")                                                              \
        for (int i = 0; i < 4; ++i)                                                    \
            _Pragma("unroll")                                                          \
            for (int j = 0; j < 4; ++j)                                                \
                acc[i][j] = __builtin_amdgcn_mfma_f32_16x16x32_bf16(af[i], bfv[j], acc[i][j], 0, 0, 0); \
        _Pragma("unroll")                                                              \
        for (int i = 0; i < 4; ++i) af[i]  = *(const bf16x8*)(arp1 + i * 1024);        \
        _Pragma("unroll")                                                              \
        for (int j = 0; j < 4; ++j) bfv[j] = *(const bf16x8*)(brp1 + j * 1024);        \
        _Pragma("unroll")                                                              \
        for (int i = 0; i < 4; ++i)                                                    \
            _Pragma("unroll")                                                          \
            for (int j = 0; j < 4; ++j)                                                \
                acc[i][j] = __builtin_amdgcn_mfma_f32_16x16x32_bf16(af[i], bfv[j], acc[i][j], 0, 0, 0); \
    }                                                                                  \
    _Pragma("unroll")                                                                  \
    for (int i = 0; i < 4; ++i) {                                                      \
        const int row = bm + wm + i * 16 + quad * 4;                                   \
        _Pragma("unroll")                                                              \
        for (int j = 0; j < 4; ++j) {                                                  \
            const int col = bn + wn + j * 16 + tr;                                     \
            OutT* op = O + (size_t)row * ldo + col;                                    \
            _Pragma("unroll")                                                          \
            for (int r = 0; r < 4; ++r) {                                              \
                float v = acc[i][j][r];                                                \
                if (EPI == 1) v = silu_f(v);                                           \
                if (ATOMIC == 1) atomicAdd((float*)(op + (size_t)r * ldo), v);         \
                else             op[(size_t)r * ldo] = (OutT)v;                        \
            }                                                                          \
        }                                                                              \
    }                                                                                  \
}

template<int EPI, int ATOMIC, typename OutT>
__global__ __launch_bounds__(256) void gemm_bf16(
    const __bf16* __restrict__ A, const __bf16* __restrict__ W, OutT* __restrict__ O,
    int M, int N, int Kslice, int lda, int ldw, int ldo)
{
    if (ATOMIC == 0) O += (size_t)blockIdx.z * (size_t)M * ldo;  // partial buffer
    const int bm = blockIdx.x * 128;
    const int bn = blockIdx.y * 128;
    const int kbase = blockIdx.z * Kslice;
    GEMM_BODY(EPI, ATOMIC, OutT, A, W, O, Kslice, lda, ldw, ldo, bm, bn, kbase)
}

// ---------------------------------------------------------------------------
// prep1: fused fp32->bf16 conversions needed before G1.
// segs: x (768 blk), w_up (4608); 256 thr x 8 elems each.
// ---------------------------------------------------------------------------
__global__ void prep1(const float* __restrict__ x, const float* __restrict__ wup,
                      __bf16* __restrict__ xb, __bf16* __restrict__ wupb)
{
    const int bid = blockIdx.x;
    if (bid < 768) cvt8(x,   xb,   (bid * 256 + threadIdx.x) * 8);
    else           cvt8(wup, wupb, ((bid - 768) * 256 + threadIdx.x) * 8);
}

// ---------------------------------------------------------------------------
// g1_fused: G1 GEMM tiles (blocks 0..1535) + w_down fp32->bf16 conversion
// (blocks 1536..19967). cvt blocks drain into CU idle tails of the GEMM.
// ---------------------------------------------------------------------------
__global__ __launch_bounds__(256) void g1_fused(
    const __bf16* __restrict__ xb, const __bf16* __restrict__ wupb,
    __bf16* __restrict__ U1b,
    const float* __restrict__ wdn, __bf16* __restrict__ wdnb)
{
    const int bid = blockIdx.x;
    if (bid < 1536) {
        const int bm = (bid & 15) * 128, bn = (bid >> 4) * 128;
        GEMM_BODY(1, 0, __bf16, xb, wupb, U1b, H_, H_, H_, DUP_, bm, bn, 0)
    } else {
        cvt8(wdn, wdnb, ((bid - 1536) * 256 + threadIdx.x) * 8);
    }
}

// ---------------------------------------------------------------------------
// conv_prep2: depthwise causal conv (K=4)+bias+silu over P0+P1 (blocks
// 0..12287) + post-G2 prep (w_oup cvt 4608, w_odown cvt 2304, pad_xp 96,
// transpose_dtw 288). All depend only on G2 / kernel inputs.
// ---------------------------------------------------------------------------
__global__ void conv_prep2(const float* __restrict__ P0, const float* __restrict__ P1,
                           const float* __restrict__ cw, const float* __restrict__ cb,
                           __bf16* __restrict__ HSb,
                           const float* __restrict__ woup, const float* __restrict__ wodn,
                           const float* __restrict__ xp, const float* __restrict__ dtw,
                           __bf16* __restrict__ woupb, __bf16* __restrict__ wodnb,
                           __bf16* __restrict__ xppad, float* __restrict__ dtwT)
{
    const int bid = blockIdx.x;
    if (bid < 12288) {
        const int t = bid * 256 + threadIdx.x;
        const int d = t % DI_;
        const int bl = t / DI_;
        const int l = bl % L_;
        const float4 w = *(const float4*)(cw + (size_t)d * 4);
        const float wk[4] = {w.x, w.y, w.z, w.w};
        float acc = cb[d];
#pragma unroll
        for (int k = 0; k < 4; ++k) {
            const int ls = l - 3 + k;
            if (ls >= 0) {
                const size_t idx = (size_t)(bl - l + ls) * DI2_ + d;
                acc += wk[k] * (P0[idx] + P1[idx]);
            }
        }
        HSb[t] = (__bf16)silu_f(acc);
        return;
    }
    const int pid = bid - 12288;
    if (pid < 4608)        cvt8(woup, woupb, (pid * 256 + threadIdx.x) * 8);
    else if (pid < 6912)   cvt8(wodn, wodnb, ((pid - 4608) * 256 + threadIdx.x) * 8);
    else if (pid < 7008) {
        const int i = ((pid - 6912) * 256 + threadIdx.x) * 8;   // < 128*1536
        const int j = i / DI_;
        bf16x8 v;
        if (j < 80) {
            const float4 a = *(const float4*)(xp + i);
            const float4 b = *(const float4*)(xp + i + 4);
            v[0] = (__bf16)a.x; v[1] = (__bf16)a.y; v[2] = (__bf16)a.z; v[3] = (__bf16)a.w;
            v[4] = (__bf16)b.x; v[5] = (__bf16)b.y; v[6] = (__bf16)b.z; v[7] = (__bf16)b.w;
        } else {
            for (int k = 0; k < 8; ++k) v[k] = (__bf16)0.f;
        }
        *(bf16x8*)(xppad + i) = v;
    } else {
        const int i = (pid - 7008) * 256 + threadIdx.x;         // < 48*1536
        const int r = i / DI_, d = i % DI_;
        dtwT[i] = dtw[(size_t)d * R_ + r];
    }
}

// ---------------------------------------------------------------------------
// split-K partial reductions (plain-store split-K -> single buffer)
// ---------------------------------------------------------------------------
__global__ void reduce_sp(const float* __restrict__ SPp, float* __restrict__ SPb)
{
    const int i = (blockIdx.x * 256 + threadIdx.x) * 4;      // < 2048*128
    float4 a = *(const float4*)(SPp + i);
#pragma unroll
    for (int z = 1; z < 8; ++z) {
        const float4 b = *(const float4*)(SPp + (size_t)z * (BL_ * SPW) + i);
        a.x += b.x; a.y += b.y; a.z += b.z; a.w += b.w;
    }
    *(float4*)(SPb + i) = a;
}

__global__ void reduce_out(const float* __restrict__ OP, float* __restrict__ out)
{
    const int i = (blockIdx.x * 256 + threadIdx.x) * 4;      // < 2048*768
    float4 a = *(const float4*)(OP + i);
#pragma unroll
    for (int z = 1; z < 8; ++z) {
        const float4 b = *(const float4*)(OP + (size_t)z * (BL_ * H_) + i);
        a.x += b.x; a.y += b.y; a.z += b.z; a.w += b.w;
    }
    *(float4*)(out + i) = a;
}

// ---------------------------------------------------------------------------
// dt[bl, d] = softplus(sum_r ts[bl, r] * dtwT[r, d] + dt_b[d])
// ---------------------------------------------------------------------------
__global__ void dt_kernel(const float* __restrict__ SP, const float* __restrict__ dtwT,
                          const float* __restrict__ dtb, float* __restrict__ DT)
{
    const int t = blockIdx.x * blockDim.x + threadIdx.x;
    const int d = t % DI_;
    const int bl = t / DI_;
    const float* ts = SP + (size_t)bl * SPW;
    float s = dtb[d];
#pragma unroll
    for (int r4 = 0; r4 < R_ / 4; ++r4) {
        const float4 tv = *(const float4*)(ts + r4 * 4);
        const float* wp = dtwT + (size_t)r4 * 4 * DI_ + d;
        s += tv.x * wp[0] + tv.y * wp[DI_] + tv.z * wp[2 * DI_] + tv.w * wp[3 * DI_];
    }
    DT[t] = (s > 20.f) ? s : log1pf(__expf(s));
}

// ---------------------------------------------------------------------------
// Chunked parallel scan, thread per (b,c,d), 16 n-states in registers.
// ---------------------------------------------------------------------------
__global__ __launch_bounds__(256) void scan_pass1(
    const float* __restrict__ DT, const __bf16* __restrict__ HSb,
    const float* __restrict__ SP, const float* __restrict__ A_log,
    float* __restrict__ Aprod, float* __restrict__ Bacc)
{
    const int t = blockIdx.x * blockDim.x + threadIdx.x;   // < B*C*DI
    const int d = t % DI_;
    const int y = t / DI_;
    const int c = y % C_;
    const int b = y / C_;
    float A[N_], s[N_], ap[N_];
    {
        const float4* alp = (const float4*)(A_log + (size_t)d * N_);
        const float4 a0 = alp[0], a1 = alp[1], a2 = alp[2], a3 = alp[3];
        const float av[N_] = {a0.x,a0.y,a0.z,a0.w, a1.x,a1.y,a1.z,a1.w,
                              a2.x,a2.y,a2.z,a2.w, a3.x,a3.y,a3.z,a3.w};
#pragma unroll
        for (int n = 0; n < N_; ++n) { A[n] = -__expf(av[n]); s[n] = 0.f; ap[n] = 1.f; }
    }
    for (int il = 0; il < CL_; ++il) {
        const size_t bl = (size_t)b * L_ + c * CL_ + il;
        const float dt = DT[bl * DI_ + d];
        const float hs = (float)HSb[bl * DI_ + d];
        const float4* Bp = (const float4*)(SP + bl * SPW + R_);
        const float4 b0 = Bp[0], b1 = Bp[1], b2 = Bp[2], b3 = Bp[3];
        const float Bv[N_] = {b0.x,b0.y,b0.z,b0.w, b1.x,b1.y,b1.z,b1.w,
                              b2.x,b2.y,b2.z,b2.w, b3.x,b3.y,b3.z,b3.w};
        const float dh = dt * hs;
#pragma unroll
        for (int n = 0; n < N_; ++n) {
            const float dA = __expf(dt * A[n]);
            s[n] = fmaf(dA, s[n], dh * Bv[n]);
            ap[n] *= dA;
        }
    }
    float4* Ap = (float4*)(Aprod + (size_t)t * N_);
    float4* Bc = (float4*)(Bacc  + (size_t)t * N_);
    Ap[0] = make_float4(ap[0], ap[1], ap[2], ap[3]);
    Ap[1] = make_float4(ap[4], ap[5], ap[6], ap[7]);
    Ap[2] = make_float4(ap[8], ap[9], ap[10], ap[11]);
    Ap[3] = make_float4(ap[12], ap[13], ap[14], ap[15]);
    Bc[0] = make_float4(s[0], s[1], s[2], s[3]);
    Bc[1] = make_float4(s[4], s[5], s[6], s[7]);
    Bc[2] = make_float4(s[8], s[9], s[10], s[11]);
    Bc[3] = make_float4(s[12], s[13], s[14], s[15]);
}

__global__ __launch_bounds__(256) void scan_pass2(
    const float* __restrict__ Aprod, const float* __restrict__ Bacc,
    float* __restrict__ Sinit)
{
    const int t = blockIdx.x * blockDim.x + threadIdx.x;    // < B*DI*N
    const int n = t & (N_ - 1);
    const int d = (t >> 4) % DI_;
    const int b = (t >> 4) / DI_;
    float s = 0.f;
    for (int c = 0; c < C_; ++c) {
        const size_t idx = (((size_t)b * C_ + c) * DI_ + d) * N_ + n;
        Sinit[idx] = s;
        s = fmaf(Aprod[idx], s, Bacc[idx]);
    }
}

__global__ __launch_bounds__(256) void scan_pass3(
    const float* __restrict__ DT, const __bf16* __restrict__ HSb,
    const float* __restrict__ SP, const float* __restrict__ P0,
    const float* __restrict__ P1, const float* __restrict__ A_log,
    const float* __restrict__ Dv, const float* __restrict__ Sinit,
    __bf16* __restrict__ Y)
{
    const int t = blockIdx.x * blockDim.x + threadIdx.x;   // < B*C*DI
    const int d = t % DI_;
    const int y = t / DI_;
    const int c = y % C_;
    const int b = y / C_;
    float A[N_], s[N_];
    {
        const float4* alp = (const float4*)(A_log + (size_t)d * N_);
        const float4 a0 = alp[0], a1 = alp[1], a2 = alp[2], a3 = alp[3];
        const float av[N_] = {a0.x,a0.y,a0.z,a0.w, a1.x,a1.y,a1.z,a1.w,
                              a2.x,a2.y,a2.z,a2.w, a3.x,a3.y,a3.z,a3.w};
#pragma unroll
        for (int n = 0; n < N_; ++n) A[n] = -__expf(av[n]);
    }
    {
        const float4* sp = (const float4*)(Sinit + (size_t)t * N_);
        const float4 s0 = sp[0], s1 = sp[1], s2 = sp[2], s3 = sp[3];
        s[0]=s0.x; s[1]=s0.y; s[2]=s0.z; s[3]=s0.w;
        s[4]=s1.x; s[5]=s1.y; s[6]=s1.z; s[7]=s1.w;
        s[8]=s2.x; s[9]=s2.y; s[10]=s2.z; s[11]=s2.w;
        s[12]=s3.x; s[13]=s3.y; s[14]=s3.z; s[15]=s3.w;
    }
    const float Dd = Dv[d];
    for (int il = 0; il < CL_; ++il) {
        const size_t bl = (size_t)b * L_ + c * CL_ + il;
        const float dt = DT[bl * DI_ + d];
        const float hs = (float)HSb[bl * DI_ + d];
        const float4* Bp = (const float4*)(SP + bl * SPW + R_);
        const float4 b0 = Bp[0], b1 = Bp[1], b2 = Bp[2], b3 = Bp[3];
        const float4 c0 = Bp[4], c1 = Bp[5], c2 = Bp[6], c3 = Bp[7];
        const float Bv[N_] = {b0.x,b0.y,b0.z,b0.w, b1.x,b1.y,b1.z,b1.w,
                              b2.x,b2.y,b2.z,b2.w, b3.x,b3.y,b3.z,b3.w};
        const float Cv[N_] = {c0.x,c0.y,c0.z,c0.w, c1.x,c1.y,c1.z,c1.w,
                              c2.x,c2.y,c2.z,c2.w, c3.x,c3.y,c3.z,c3.w};
        const float dh = dt * hs;
        float acc = 0.f;
#pragma unroll
        for (int n = 0; n < N_; ++n) {
            const float dA = __expf(dt * A[n]);
            s[n] = fmaf(dA, s[n], dh * Bv[n]);
            acc = fmaf(s[n], Cv[n], acc);
        }
        const size_t gidx = bl * DI2_ + DI_ + d;
        const float g = P0[gidx] + P1[gidx];
        Y[bl * DI_ + d] = (__bf16)((acc + hs * Dd) * silu_f(g));
    }
}

extern "C" void kernel_launch(void* const* d_in, const int* in_sizes, int n_in,
                              void* d_out, int out_size, void* d_ws, size_t ws_size,
                              hipStream_t stream) {
    const float* x        = (const float*)d_in[0];
    const float* w_up     = (const float*)d_in[1];
    const float* w_down   = (const float*)d_in[2];
    const float* conv_w   = (const float*)d_in[3];
    const float* conv_b   = (const float*)d_in[4];
    const float* x_proj_w = (const float*)d_in[5];
    const float* dt_w     = (const float*)d_in[6];
    const float* dt_b     = (const float*)d_in[7];
    const float* A_log    = (const float*)d_in[8];
    const float* Dvec     = (const float*)d_in[9];
    const float* w_oup    = (const float*)d_in[10];
    const float* w_odown  = (const float*)d_in[11];
    float* out = (float*)d_out;

    // ---- workspace layout, peak 176.2 MB (183+ proven safe) ----
    char* base = (char*)d_ws;
    __bf16* x_b      = (__bf16*)base;                      //  3,145,728
    __bf16* wup_b    = (__bf16*)(base + 3145728);          // 18,874,368
    float*  P0       = (float*)base;                       // 25,165,824
    float*  P1       = (float*)(base + 25165824);          // 25,165,824
    float*  OP       = (float*)base;                       // 50,331,648 (G5 partials, after p3)
    char* r2 = base + 50331648;
    __bf16* wdown_b  = (__bf16*)r2;                        // 75,497,472
    __bf16* HSb      = (__bf16*)r2;                        //  6,291,456
    float*  SPb      = (float*)(r2 + 6291456);             //  1,048,576
    float*  SPp      = (float*)(r2 + 7340032);             //  8,388,608 (8 partials)
    float*  DTb      = (float*)(r2 + 15728640);            // 12,582,912
    __bf16* Yb       = (__bf16*)(r2 + 28311552);           //  6,291,456
    __bf16* XPpad    = (__bf16*)(r2 + 34603008);           //    393,216
    float*  dtwT     = (float*)(r2 + 34996224);            //    294,912
    __bf16* woup_b   = (__bf16*)(r2 + 35291136);           // 18,874,368
    __bf16* wodown_b = (__bf16*)(r2 + 54165504);           //  9,437,184 (ends 63.6M < 75.5M)
    char* r3 = r2 + 75497472;
    __bf16* U1b      = (__bf16*)r3;                        // 50,331,648
    __bf16* U2b      = (__bf16*)r3;                        // 25,165,824 (after p2)
    float*  Aprod    = (float*)r3;                         // 12,582,912
    float*  Bacc     = (float*)(r3 + 12582912);            // 12,582,912
    float*  Sinit    = (float*)(r3 + 25165824);            // 12,582,912

    // prep: x, w_up -> bf16
    prep1<<<5376, 256, 0, stream>>>(x, w_up, x_b, wup_b);

    // G1 (1536 tile blocks) + w_down cvt (18432 blocks) in ONE launch
    g1_fused<<<19968, 256, 0, stream>>>(x_b, wup_b, U1b, w_down, wdown_b);

    // G2: P = U1 @ w_down^T  [2048 x 3072], K=12288, split-K x2 plain-store
    gemm_bf16<0, 0, float><<<dim3(16, 24, 2), 256, 0, stream>>>(
        U1b, wdown_b, P0, BL_, DI2_, DUP_ / 2, DUP_, DUP_, DI2_);

    // conv+silu over P0+P1 -> HSb (12288 blocks) + post-G2 prep (7296 blocks)
    conv_prep2<<<19584, 256, 0, stream>>>(P0, P1, conv_w, conv_b, HSb,
                                          w_oup, w_odown, x_proj_w, dt_w,
                                          woup_b, wodown_b, XPpad, dtwT);

    // ssm projection: SP[2048][128] = HSb @ XPpad^T, split-K x8 plain-store + reduce
    gemm_bf16<0, 0, float><<<dim3(16, 1, 8), 256, 0, stream>>>(
        HSb, XPpad, SPp, BL_, SPW, DI_ / 8, DI_, DI_, SPW);
    reduce_sp<<<(BL_ * SPW) / 1024, 256, 0, stream>>>(SPp, SPb);

    // dt -> DT
    dt_kernel<<<(BL_ * DI_) / 256, 256, 0, stream>>>(SPb, dtwT, dt_b, DTb);

    // chunked scan (C=64 chunks of 16)
    scan_pass1<<<(B_ * C_ * DI_) / 256, 256, 0, stream>>>(DTb, HSb, SPb, A_log, Aprod, Bacc);
    scan_pass2<<<(B_ * DI_ * N_) / 256, 256, 0, stream>>>(Aprod, Bacc, Sinit);
    scan_pass3<<<(B_ * C_ * DI_) / 256, 256, 0, stream>>>(
        DTb, HSb, SPb, P0, P1, A_log, Dvec, Sinit, Yb);

    // G4: U2b = silu(Y @ w_oup^T)   [2048 x 6144], K=1536
    gemm_bf16<1, 0, __bf16><<<dim3(16, 48, 1), 256, 0, stream>>>(
        Yb, woup_b, U2b, BL_, DOUT_, DI_, DI_, DI_, DOUT_);

    // G5: out = U2 @ w_odown^T  [2048 x 768], K=6144, split-K x8 plain-store
    gemm_bf16<0, 0, float><<<dim3(16, 6, 8), 256, 0, stream>>>(
        U2b, wodown_b, OP, BL_, H_, DOUT_ / 8, DOUT_, DOUT_, H_);
    reduce_out<<<(BL_ * H_) / 1024, 256, 0, stream>>>(OP, out);
}